// Round 1
// baseline (309.248 us; speedup 1.0000x reference)
//
#include <hip/hip_runtime.h>
#include <stdint.h>

typedef unsigned short u16;
typedef __attribute__((__ext_vector_type__(4))) float f32x4;
typedef __attribute__((__ext_vector_type__(8))) __bf16 bf16x8;
typedef __attribute__((__ext_vector_type__(4))) unsigned short u16x4;

#define DEV static __device__ __forceinline__

DEV u16 f2b(float f) {
  union { float f; unsigned u; } v; v.f = f;
  unsigned r = v.u + 0x7FFFu + ((v.u >> 16) & 1u);   // RNE to bf16
  return (u16)(r >> 16);
}

typedef const __attribute__((address_space(1))) void* gas_t;
typedef __attribute__((address_space(3))) void* las_t;

// async global->LDS, 16B per lane; LDS dest = wave-uniform base + lane*16
DEV void gl_lds16(const void* g, void* l) {
  __builtin_amdgcn_global_load_lds((gas_t)(uintptr_t)g, (las_t)(uint32_t)(uintptr_t)l,
                                   16, 0, 0);
}

// ---------------- fp32 -> bf16 convert ----------------
__global__ void cvt4(const float* __restrict__ s, u16* __restrict__ d, int n4) {
  const int i = blockIdx.x * 256 + threadIdx.x;
  if (i >= n4) return;
  const float4 f = reinterpret_cast<const float4*>(s)[i];
  u16x4 o;
  o.x = f2b(f.x); o.y = f2b(f.y); o.z = f2b(f.z); o.w = f2b(f.w);
  reinterpret_cast<u16x4*>(d)[i] = o;
}

// ---------------- GEMM C = A * B^T (bf16, MFMA 16x16x32) ----------------
// 128x128 tile, BK=32, 4 waves (2x2), m97 structure.
// MODE 0: QKV epilogue -> Q[b,h,n,d], K[b,h,n,d], Vt[b,h,d,n] (bf16)
// MODE 1: fp32 out + bias
template<int MODE>
__global__ __launch_bounds__(256, 2) void gemm_bt(
    const u16* __restrict__ A, const u16* __restrict__ B, int K, int tiles_n,
    u16* __restrict__ Qo, u16* __restrict__ Ko, u16* __restrict__ Vo,
    float* __restrict__ Fo, const float* __restrict__ bias, int N)
{
  __shared__ u16 As[128 * 32];
  __shared__ u16 Bs[128 * 32];
  const int tm = blockIdx.x / tiles_n, tn = blockIdx.x % tiles_n;
  const int tid = threadIdx.x, wid = tid >> 6, lane = tid & 63;
  const int wr = wid >> 1, wc = wid & 1;
  const int lr = lane & 15, lk = lane >> 4;

  const f32x4 fz = {0.f, 0.f, 0.f, 0.f};
  f32x4 acc[4][4];
#pragma unroll
  for (int i = 0; i < 4; i++)
#pragma unroll
    for (int j = 0; j < 4; j++) acc[i][j] = fz;

  const u16* Ab = A + (size_t)tm * 128 * K;
  const u16* Bb = B + (size_t)tn * 128 * K;

  // staging: 512 16B chunks per tile; chunk c -> row c>>2, chunk-slot c&3.
  // Bank-conflict swizzle (both-sides): global slot = lds slot ^ ((row>>1)&3)
  const int ca = tid, cb2 = tid + 256;
  const int ra = ca >> 2,  ka = ((ca  & 3) ^ ((ra  >> 1) & 3)) * 8;
  const int rb = cb2 >> 2, kb = ((cb2 & 3) ^ ((rb  >> 1) & 3)) * 8;

  for (int k0 = 0; k0 < K; k0 += 32) {
    __syncthreads();
    gl_lds16(Ab + (size_t)ra * K + k0 + ka, &As[wid * 512]);
    gl_lds16(Ab + (size_t)rb * K + k0 + kb, &As[2048 + wid * 512]);
    gl_lds16(Bb + (size_t)ra * K + k0 + ka, &Bs[wid * 512]);
    gl_lds16(Bb + (size_t)rb * K + k0 + kb, &Bs[2048 + wid * 512]);
    asm volatile("s_waitcnt vmcnt(0)" ::: "memory");
    __syncthreads();
    bf16x8 af[4], bf[4];
#pragma unroll
    for (int i = 0; i < 4; i++) {
      const int row = wr * 64 + i * 16 + lr;
      af[i] = *reinterpret_cast<const bf16x8*>(&As[row * 32 + (lk ^ ((row >> 1) & 3)) * 8]);
    }
#pragma unroll
    for (int j = 0; j < 4; j++) {
      const int row = wc * 64 + j * 16 + lr;
      bf[j] = *reinterpret_cast<const bf16x8*>(&Bs[row * 32 + (lk ^ ((row >> 1) & 3)) * 8]);
    }
#pragma unroll
    for (int i = 0; i < 4; i++)
#pragma unroll
      for (int j = 0; j < 4; j++)
        acc[i][j] = __builtin_amdgcn_mfma_f32_16x16x32_bf16(af[i], bf[j], acc[i][j], 0, 0, 0);
  }

  const int row0 = tm * 128 + wr * 64;
  if constexpr (MODE == 0) {
#pragma unroll
    for (int i = 0; i < 4; i++) {
#pragma unroll
      for (int j = 0; j < 4; j++) {
        const int e0 = tn * 128 + wc * 64 + j * 16;  // global out-channel base (uniform/frag)
        const int mat = e0 >> 10;                    // 0=Q 1=K 2=V
        const int h = (e0 & 1023) >> 6;
        const int d = (e0 & 63) + lr;
#pragma unroll
        for (int r = 0; r < 4; r++) {
          const int m = row0 + i * 16 + lk * 4 + r;  // C layout: row=(lane>>4)*4+reg
          const int bb = m >> 11, n = m & 2047;
          const u16 val = f2b(acc[i][j][r]);
          if (mat == 0)      Qo[((bb * 16 + h) * 2048 + n) * 64 + d] = val;
          else if (mat == 1) Ko[((bb * 16 + h) * 2048 + n) * 64 + d] = val;
          else               Vo[((bb * 16 + h) * 64 + d) * 2048 + n] = val;
        }
      }
    }
  } else {
#pragma unroll
    for (int i = 0; i < 4; i++) {
#pragma unroll
      for (int j = 0; j < 4; j++) {
        const int col = tn * 128 + wc * 64 + j * 16 + lr;
        const float bv = bias[col];
#pragma unroll
        for (int r = 0; r < 4; r++) {
          const int m = row0 + i * 16 + lk * 4 + r;
          Fo[(size_t)m * N + col] = acc[i][j][r] + bv;
        }
      }
    }
  }
}

// ---------------- flash attention ----------------
// grid: 64 (b*h) x 16 q-tiles. 256 thr / 4 waves; wave owns 32 q-rows.
// KV tile = 128. Q hoisted to regs. K/V staged via gl_lds with pre-swizzled
// source; P round-trips LDS with XOR swizzle.
__global__ __launch_bounds__(256, 2) void attn_fwd(
    const u16* __restrict__ Q, const u16* __restrict__ K, const u16* __restrict__ Vt,
    u16* __restrict__ O)
{
  __shared__ u16 Ks[128 * 64];
  __shared__ u16 Vs[64 * 128];
  __shared__ u16 Ps[128 * 128];
  const int bh = blockIdx.x >> 4, qt = blockIdx.x & 15;
  const int tid = threadIdx.x, w = tid >> 6, lane = tid & 63;
  const int lr = lane & 15, lk = lane >> 4;
  const u16* Qp = Q + ((size_t)bh * 2048 + qt * 128) * 64;
  const u16* Kp = K + (size_t)bh * 2048 * 64;
  const u16* Vp = Vt + (size_t)bh * 64 * 2048;

  bf16x8 qfr[2][2];
#pragma unroll
  for (int qf = 0; qf < 2; qf++)
#pragma unroll
    for (int kk = 0; kk < 2; kk++)
      qfr[qf][kk] = *reinterpret_cast<const bf16x8*>(
          &Qp[(w * 32 + qf * 16 + lr) * 64 + kk * 32 + lk * 8]);

  const f32x4 fz = {0.f, 0.f, 0.f, 0.f};
  f32x4 oacc[2][4];
  float ms[2][4], ls[2][4];
#pragma unroll
  for (int qf = 0; qf < 2; qf++) {
#pragma unroll
    for (int df = 0; df < 4; df++) oacc[qf][df] = fz;
#pragma unroll
    for (int r = 0; r < 4; r++) { ms[qf][r] = -1e30f; ls[qf][r] = 0.f; }
  }

  for (int kt = 0; kt < 16; kt++) {
    __syncthreads();
#pragma unroll
    for (int j = 0; j < 4; j++) {
      const int c = tid + 256 * j;
      const int rk = c >> 3, ck = ((c & 7) ^ (rk & 7)) * 8;       // K swizzle
      gl_lds16(Kp + (size_t)kt * 8192 + rk * 64 + ck, &Ks[j * 2048 + w * 512]);
      const int rv = c >> 4, cv = ((c & 15) ^ (rv & 7)) * 8;      // V swizzle
      gl_lds16(Vp + (size_t)rv * 2048 + kt * 128 + cv, &Vs[j * 2048 + w * 512]);
    }
    asm volatile("s_waitcnt vmcnt(0)" ::: "memory");
    __syncthreads();

    // S = Q K^T
    f32x4 sacc[2][8];
#pragma unroll
    for (int qf = 0; qf < 2; qf++)
#pragma unroll
      for (int kf = 0; kf < 8; kf++) sacc[qf][kf] = fz;
#pragma unroll
    for (int kk = 0; kk < 2; kk++) {
#pragma unroll
      for (int kf = 0; kf < 8; kf++) {
        const int row = kf * 16 + lr;
        bf16x8 kfr = *reinterpret_cast<const bf16x8*>(
            &Ks[row * 64 + (((kk * 4 + lk) ^ (row & 7)) * 8)]);
        sacc[0][kf] = __builtin_amdgcn_mfma_f32_16x16x32_bf16(qfr[0][kk], kfr, sacc[0][kf], 0, 0, 0);
        sacc[1][kf] = __builtin_amdgcn_mfma_f32_16x16x32_bf16(qfr[1][kk], kfr, sacc[1][kf], 0, 0, 0);
      }
    }

    // online softmax (rows replicated across 16-lane groups)
    constexpr float scale = 0.125f;  // 1/sqrt(64)
#pragma unroll
    for (int qf = 0; qf < 2; qf++) {
      float mt[4], rs[4];
#pragma unroll
      for (int r = 0; r < 4; r++) {
        float v = sacc[qf][0][r];
#pragma unroll
        for (int kf = 1; kf < 8; kf++) v = fmaxf(v, sacc[qf][kf][r]);
        mt[r] = v;
      }
#pragma unroll
      for (int off = 1; off < 16; off <<= 1)
#pragma unroll
        for (int r = 0; r < 4; r++) mt[r] = fmaxf(mt[r], __shfl_xor(mt[r], off));
#pragma unroll
      for (int r = 0; r < 4; r++) {
        const float mn = fmaxf(ms[qf][r], mt[r] * scale);
        const float alpha = __expf(ms[qf][r] - mn);
        ms[qf][r] = mn;
        ls[qf][r] *= alpha;
#pragma unroll
        for (int df = 0; df < 4; df++) oacc[qf][df][r] *= alpha;
        rs[r] = 0.f;
      }
#pragma unroll
      for (int kf = 0; kf < 8; kf++) {
#pragma unroll
        for (int r = 0; r < 4; r++) {
          const float p = __expf(sacc[qf][kf][r] * scale - ms[qf][r]);
          rs[r] += p;
          const int prow = w * 32 + qf * 16 + lk * 4 + r;
          Ps[(prow * 128 + kf * 16 + lr) ^ ((prow & 7) << 3)] = f2b(p);
        }
      }
#pragma unroll
      for (int off = 1; off < 16; off <<= 1)
#pragma unroll
        for (int r = 0; r < 4; r++) rs[r] += __shfl_xor(rs[r], off);
#pragma unroll
      for (int r = 0; r < 4; r++) ls[qf][r] += rs[r];
    }

    // O += P V   (P rows are own-wave: no barrier needed; lgkmcnt orders LDS)
    bf16x8 pa[2][4];
#pragma unroll
    for (int qf = 0; qf < 2; qf++)
#pragma unroll
      for (int kk = 0; kk < 4; kk++) {
        const int prow = w * 32 + qf * 16 + lr;
        pa[qf][kk] = *reinterpret_cast<const bf16x8*>(
            &Ps[prow * 128 + (((kk * 4 + lk) ^ (prow & 7)) * 8)]);
      }
#pragma unroll
    for (int df = 0; df < 4; df++) {
#pragma unroll
      for (int kk = 0; kk < 4; kk++) {
        const int vrow = df * 16 + lr;
        bf16x8 vfr = *reinterpret_cast<const bf16x8*>(
            &Vs[vrow * 128 + (((kk * 4 + lk) ^ (vrow & 7)) * 8)]);
        oacc[0][df] = __builtin_amdgcn_mfma_f32_16x16x32_bf16(pa[0][kk], vfr, oacc[0][df], 0, 0, 0);
        oacc[1][df] = __builtin_amdgcn_mfma_f32_16x16x32_bf16(pa[1][kk], vfr, oacc[1][df], 0, 0, 0);
      }
    }
  }

  const int b = bh >> 4, h = bh & 15;
#pragma unroll
  for (int qf = 0; qf < 2; qf++) {
    float inv[4];
#pragma unroll
    for (int r = 0; r < 4; r++) inv[r] = 1.f / ls[qf][r];
#pragma unroll
    for (int df = 0; df < 4; df++)
#pragma unroll
      for (int r = 0; r < 4; r++) {
        const int n = qt * 128 + w * 32 + qf * 16 + lk * 4 + r;
        O[((size_t)b * 2048 + n) * 1024 + h * 64 + df * 16 + lr] =
            f2b(oacc[qf][df][r] * inv[r]);
      }
  }
}

// ---------------- launcher ----------------
extern "C" void kernel_launch(void* const* d_in, const int* in_sizes, int n_in,
                              void* d_out, int out_size, void* d_ws, size_t ws_size,
                              hipStream_t stream) {
  const float* x  = (const float*)d_in[0];
  const float* Wq = (const float*)d_in[1];
  const float* Wk = (const float*)d_in[2];
  const float* Wv = (const float*)d_in[3];
  const float* Wo = (const float*)d_in[4];
  const float* bo = (const float*)d_in[5];
  float* out = (float*)d_out;

  u16* ws   = (u16*)d_ws;
  u16* xb   = ws;                  // 8192x1024 bf16; reused as attn_out after GEMM1
  u16* Wqkv = xb + 8388608;        // 3072x1024
  u16* Wob  = Wqkv + 3145728;      // 1024x1024
  u16* Qb   = Wob + 1048576;       // [b,h,n,d]
  u16* Kb   = Qb + 8388608;        // [b,h,n,d]
  u16* Vtb  = Kb + 8388608;        // [b,h,d,n]

  cvt4<<<8192, 256, 0, stream>>>(x,  xb, 2097152);
  cvt4<<<1024, 256, 0, stream>>>(Wq, Wqkv,            262144);
  cvt4<<<1024, 256, 0, stream>>>(Wk, Wqkv + 1048576,  262144);
  cvt4<<<1024, 256, 0, stream>>>(Wv, Wqkv + 2097152,  262144);
  cvt4<<<1024, 256, 0, stream>>>(Wo, Wob, 262144);

  // QKV: C[8192x3072] = xb * Wqkv^T, routed into Q/K/Vt
  gemm_bt<0><<<64 * 24, 256, 0, stream>>>(xb, Wqkv, 1024, 24,
                                          Qb, Kb, Vtb, nullptr, nullptr, 3072);
  // attention -> xb as [b,n,h*64+d] bf16
  attn_fwd<<<1024, 256, 0, stream>>>(Qb, Kb, Vtb, xb);
  // out proj: fp32 out = xb * Wo^T + bo
  gemm_bt<1><<<64 * 8, 256, 0, stream>>>(xb, Wob, 1024, 8,
                                         nullptr, nullptr, nullptr, out, bo, 1024);
}